// Round 1
// baseline (159.451 us; speedup 1.0000x reference)
//
#include <hip/hip_runtime.h>

// Problem constants (from reference): B=64, L=512, H=768, W=255
#define B_ 64
#define L_ 512
#define H_ 768
#define W_ 255
#define H4 (H_ / 4)   // 192 float4 per token row

// Kernel 1: per-batch exclusive prefix sum of words_lengths, +1 (token 0 is CLS).
// starts[b*W + w] = 1 + sum_{j<w} lengths[b*W + j]
// One wave (64 threads) per batch; shuffle-based inclusive scan over 4 chunks.
__global__ void scan_starts(const int* __restrict__ lengths, int* __restrict__ starts) {
    int b = blockIdx.x;
    const int* len = lengths + b * W_;
    int* st = starts + b * W_;
    int lane = threadIdx.x;  // 0..63
    int carry = 1;           // word 0 starts at token 1
    for (int base = 0; base < W_; base += 64) {
        int i = base + lane;
        int v = (i < W_) ? len[i] : 0;
        int s = v;
        #pragma unroll
        for (int off = 1; off < 64; off <<= 1) {
            int u = __shfl_up(s, off, 64);
            if (lane >= off) s += u;
        }
        if (i < W_) st[i] = carry + (s - v);   // exclusive scan + carry
        carry += __shfl(s, 63, 64);            // total of this chunk
    }
}

// Kernel 2: one block per (word, batch); 192 threads, one float4 of H each.
// blockIdx.x == W_ is the CLS-copy slot.
__global__ __launch_bounds__(H4) void word_mean(
        const float* __restrict__ seq,
        const int* __restrict__ lengths,
        const int* __restrict__ starts,
        float* __restrict__ cls_out,
        float* __restrict__ ctx_out) {
    int w = blockIdx.x;
    int b = blockIdx.y;
    int t = threadIdx.x;  // 0..191
    const float4* base = (const float4*)(seq + (size_t)b * L_ * H_);

    if (w == W_) {
        // cls_output[b,:] = seq[b, 0, :]
        ((float4*)cls_out)[(size_t)b * H4 + t] = base[t];
        return;
    }

    int len   = lengths[b * W_ + w];   // wave-uniform scalar loads
    int start = starts [b * W_ + w];

    float4 acc = make_float4(0.f, 0.f, 0.f, 0.f);
    if (len > 0) {
        int end = start + len;
        if (end > L_) end = L_;        // safety clamp (can't trigger for this data)
        for (int tok = start; tok < end; ++tok) {
            float4 v = base[(size_t)tok * H4 + t];
            acc.x += v.x; acc.y += v.y; acc.z += v.z; acc.w += v.w;
        }
        float inv = 1.0f / (float)len;
        acc.x *= inv; acc.y *= inv; acc.z *= inv; acc.w *= inv;
    }
    // len <= 0 -> zeros (matches reference's where-clause)
    ((float4*)ctx_out)[((size_t)b * W_ + w) * H4 + t] = acc;
}

extern "C" void kernel_launch(void* const* d_in, const int* in_sizes, int n_in,
                              void* d_out, int out_size, void* d_ws, size_t ws_size,
                              hipStream_t stream) {
    const float* seq     = (const float*)d_in[0];   // (B, L, H) fp32
    const int*   lengths = (const int*)d_in[1];     // (B, W) int32

    float* cls_out = (float*)d_out;                        // (B, H)
    float* ctx_out = (float*)d_out + (size_t)B_ * H_;      // (B, W, H)

    int* starts = (int*)d_ws;  // B*W ints = 65280 B of scratch

    scan_starts<<<B_, 64, 0, stream>>>(lengths, starts);

    dim3 grid(W_ + 1, B_);   // 256 x 64 blocks
    word_mean<<<grid, H4, 0, stream>>>(seq, lengths, starts, cls_out, ctx_out);
}